// Round 7
// baseline (1391.439 us; speedup 1.0000x reference)
//
#include <hip/hip_runtime.h>
#include <hip/hip_bf16.h>
#include <hip/hip_cooperative_groups.h>

namespace cg = cooperative_groups;

// CharDecoder: T=21, B=4096, H=1024, E=50, V=96
// d_out: scores(T,B,V) fp32 | h_T(B,H) | c_T(B,H)

#define T_STEPS 21
#define BSZ 4096
#define HDIM 1024
#define VOCAB 96
#define EDIM 50

typedef __attribute__((ext_vector_type(8))) short short8;
typedef __attribute__((ext_vector_type(4))) float f32x4;

#define GLL16(g, l)                                                        \
  __builtin_amdgcn_global_load_lds(                                        \
      (const __attribute__((address_space(1))) void*)(g),                  \
      (__attribute__((address_space(3))) void*)(l), 16, 0, 0)

__device__ __forceinline__ float sigmoidf_fast(float x) {
  return 1.0f / (1.0f + __expf(-x));
}
__device__ __forceinline__ float tanhf_fast(float x) {
  return 2.0f / (1.0f + __expf(-2.0f * x)) - 1.0f;
}

// ---- prep: fp32 -> bf16 weight/state conversion -------------------------
__global__ void prep_convert(const float* __restrict__ Whh_f,
                             const float* __restrict__ Wout_f,
                             const float* __restrict__ h0,
                             __hip_bfloat16* __restrict__ Whh,
                             __hip_bfloat16* __restrict__ Wout,
                             __hip_bfloat16* __restrict__ hb0) {
  int idx = blockIdx.x * 256 + threadIdx.x;
  if (idx < 4 * HDIM * HDIM) {
    Whh[idx] = __float2bfloat16(Whh_f[idx]);
    hb0[idx] = __float2bfloat16(h0[idx]);
  }
  if (idx < VOCAB * HDIM) Wout[idx] = __float2bfloat16(Wout_f[idx]);
}

// ---- prep: P[v][g] fp32 and Pb (bf16, per-j-block) gate tables ----------
__global__ void prep_ptable(const float* __restrict__ emb,
                            const float* __restrict__ Wih,
                            const float* __restrict__ bih,
                            const float* __restrict__ bhh,
                            float* __restrict__ P,
                            __hip_bfloat16* __restrict__ Pb) {
  int idx = blockIdx.x * 256 + threadIdx.x;  // 96*4096
  int v = idx >> 12, g = idx & 4095;         // g = gate*1024 + j
  int gate = g >> 10, j = g & 1023;
  const float* er = emb + v * EDIM;
  const float* wr = Wih + g * EDIM;
  float s = bih[g] + bhh[g];
#pragma unroll 10
  for (int e = 0; e < EDIM; ++e) s += er[e] * wr[e];
  P[idx] = s;
  Pb[(size_t)(j >> 5) * 12288 + v * 128 + gate * 32 + (j & 31)] =
      __float2bfloat16(s);
}

// ==== persistent cooperative kernel: all 21 steps + overlapped scores ====
// 1056 blocks: 0..1023 gate-tiles (128 rows x 32 units, R5-proven K-loop),
// 1024..1055 score-tiles (128 rows x 96 vocab) computing scores for the
// PREVIOUS step concurrently with the current step's gates. c state lives
// in registers for the whole sequence. LDS = 32 KB -> 5 blocks/CU.
__global__ __launch_bounds__(256, 5) void lstm_persistent(
    const int* __restrict__ ids_all,           // T x B
    const __hip_bfloat16* __restrict__ Whh,    // 4H x H
    const float* __restrict__ P,               // V x 4H (fp32)
    const __hip_bfloat16* __restrict__ Wout,   // V x H
    const float* __restrict__ bout,            // V
    const float* __restrict__ c0,              // B x H
    __hip_bfloat16* __restrict__ h0buf,        // B x H (holds h_{t-1}, t even)
    __hip_bfloat16* __restrict__ h1buf,        // B x H
    float* __restrict__ scores,                // T x B x V
    float* __restrict__ hT,                    // B x H
    float* __restrict__ cT)                    // B x H
{
  __shared__ __align__(16) char smem[32768];
  __hip_bfloat16* sA = (__hip_bfloat16*)smem;            // [128][64]
  __hip_bfloat16* sB = (__hip_bfloat16*)(smem + 16384);  // [128][64]/[96][64]

  cg::grid_group gg_grid = cg::this_grid();

  const int tid = threadIdx.x;
  const int wave = tid >> 6;
  const int lane = tid & 63;
  const int bid = blockIdx.x;

  const int lrow = lane >> 3;                // 0..7
  const int lcol = ((lane & 7) ^ lrow) * 8;  // XOR-swizzled chunk (elems)
  const int u16 = lane & 15;
  const int k16q = lane >> 4;

  if (bid < 1024) {
    // ---------------- gate block ----------------
    const int jt = (bid & 7) * 4 + ((bid >> 3) & 3);  // XCD swizzle
    const int mt = bid >> 5;
    const int m0 = mt * 128;
    const int j0 = jt * 32;
    const int mw = (wave >> 1) * 64;
    const int gn = wave & 1;
    const int jo = gn * 16 + u16;
    const int j = j0 + jo;
    const int rb = m0 + mw + k16q * 4;

    int brow_g[4];
#pragma unroll
    for (int i = 0; i < 4; ++i) {
      int n = wave * 32 + i * 8 + lrow;  // n' in [0,128)
      int q = n >> 6, gate = (n >> 4) & 3, u = n & 15;
      brow_g[i] = gate * HDIM + j0 + q * 16 + u;
    }

    // cell state for this tile lives in registers across all steps
    float creg[4][4];
#pragma unroll
    for (int mi = 0; mi < 4; ++mi)
#pragma unroll
      for (int r = 0; r < 4; ++r)
        creg[mi][r] = c0[(size_t)(rb + mi * 16 + r) * HDIM + j];

    for (int t = 0; t <= T_STEPS; ++t) {
      if (t < T_STEPS) {
        const __hip_bfloat16* hprev = (t & 1) ? h1buf : h0buf;
        __hip_bfloat16* hnext = (t & 1) ? h0buf : h1buf;
        const int* ids = ids_all + t * BSZ;
        const __hip_bfloat16* Abase =
            hprev + (size_t)(m0 + wave * 32 + lrow) * HDIM + lcol;

        f32x4 acc[4][4] = {};
        for (int k0 = 0; k0 < HDIM; k0 += 64) {
#pragma unroll
          for (int i = 0; i < 4; ++i) {
            GLL16(Abase + i * 8 * HDIM + k0, &sA[(wave * 32 + i * 8) * 64]);
            GLL16(Whh + (size_t)brow_g[i] * HDIM + k0 + lcol,
                  &sB[(wave * 32 + i * 8) * 64]);
          }
          __syncthreads();
#pragma unroll
          for (int kk = 0; kk < 64; kk += 32) {
            const int sl = (((kk >> 3) + k16q) ^ (u16 & 7)) * 8;
            short8 af[4], bf[4];
#pragma unroll
            for (int mi = 0; mi < 4; ++mi)
              af[mi] = *(const short8*)&sA[(mw + mi * 16 + u16) * 64 + sl];
#pragma unroll
            for (int ni = 0; ni < 4; ++ni)
              bf[ni] =
                  *(const short8*)&sB[(gn * 64 + ni * 16 + u16) * 64 + sl];
#pragma unroll
            for (int mi = 0; mi < 4; ++mi)
#pragma unroll
              for (int ni = 0; ni < 4; ++ni)
                acc[mi][ni] = __builtin_amdgcn_mfma_f32_16x16x32_bf16(
                    af[mi], bf[ni], acc[mi][ni], 0, 0, 0);
          }
          __syncthreads();
        }

        // epilogue: gates + in-register cell update
#pragma unroll
        for (int mi = 0; mi < 4; ++mi) {
#pragma unroll
          for (int r = 0; r < 4; ++r) {
            int row = rb + mi * 16 + r;
            int id = ids[row];
            const float* Pr = P + (size_t)id * 4096 + j;
            float iv = acc[mi][0][r] + Pr[0];
            float fv = acc[mi][1][r] + Pr[1024];
            float gv = acc[mi][2][r] + Pr[2048];
            float ov = acc[mi][3][r] + Pr[3072];
            iv = sigmoidf_fast(iv);
            fv = sigmoidf_fast(fv);
            gv = tanhf_fast(gv);
            ov = sigmoidf_fast(ov);
            float cc = fv * creg[mi][r] + iv * gv;
            creg[mi][r] = cc;
            float hh = ov * tanhf_fast(cc);
            size_t off = (size_t)row * HDIM + j;
            hnext[off] = __float2bfloat16(hh);
            if (t == T_STEPS - 1) {
              hT[off] = hh;
              cT[off] = cc;
            }
          }
        }
      }
      if (t < T_STEPS) gg_grid.sync();
    }
  } else {
    // ---------------- scores block (lags gates by one step) -------------
    const int sb = bid - 1024;  // 0..31
    const long r0 = (long)sb * 128;
    for (int t = 0; t <= T_STEPS; ++t) {
      if (t >= 1) {
        const __hip_bfloat16* h = (t & 1) ? h1buf : h0buf;  // h_{t-1}
        float* out = scores + (size_t)(t - 1) * BSZ * VOCAB;
        f32x4 acc[2][6] = {};
        for (int k0 = 0; k0 < HDIM; k0 += 64) {
#pragma unroll
          for (int i = 0; i < 4; ++i)  // A: 32 rows/wave
            GLL16(h + (r0 + wave * 32 + i * 8 + lrow) * HDIM + k0 + lcol,
                  &sA[(wave * 32 + i * 8) * 64]);
#pragma unroll
          for (int i = 0; i < 3; ++i)  // W: 24 rows/wave (96 total)
            GLL16(Wout + (size_t)(wave * 24 + i * 8 + lrow) * HDIM + k0 + lcol,
                  &sB[(wave * 24 + i * 8) * 64]);
          __syncthreads();
#pragma unroll
          for (int kk = 0; kk < 64; kk += 32) {
            const int sl = (((kk >> 3) + k16q) ^ (u16 & 7)) * 8;
            short8 af[2], bf[6];
#pragma unroll
            for (int mi = 0; mi < 2; ++mi)
              af[mi] =
                  *(const short8*)&sA[(wave * 32 + mi * 16 + u16) * 64 + sl];
#pragma unroll
            for (int ni = 0; ni < 6; ++ni)
              bf[ni] = *(const short8*)&sB[(ni * 16 + u16) * 64 + sl];
#pragma unroll
            for (int mi = 0; mi < 2; ++mi)
#pragma unroll
              for (int ni = 0; ni < 6; ++ni)
                acc[mi][ni] = __builtin_amdgcn_mfma_f32_16x16x32_bf16(
                    af[mi], bf[ni], acc[mi][ni], 0, 0, 0);
          }
          __syncthreads();
        }
#pragma unroll
        for (int ni = 0; ni < 6; ++ni) {
          int v = ni * 16 + u16;
          float bv = bout[v];
#pragma unroll
          for (int mi = 0; mi < 2; ++mi)
#pragma unroll
            for (int r = 0; r < 4; ++r) {
              long grow = r0 + wave * 32 + mi * 16 + k16q * 4 + r;
              out[grow * VOCAB + v] = acc[mi][ni][r] + bv;
            }
        }
      }
      if (t < T_STEPS) gg_grid.sync();
    }
  }
}

// ==================== fallback path (R5-proven kernels) ====================
template <bool LAST>
__global__ __launch_bounds__(256, 3) void lstm_step_kernel(
    const int* __restrict__ ids, const __hip_bfloat16* __restrict__ hprev,
    const __hip_bfloat16* __restrict__ Whh,
    const __hip_bfloat16* __restrict__ Pb, const float* __restrict__ c_in,
    float* __restrict__ c_out, __hip_bfloat16* __restrict__ hnext,
    float* __restrict__ hf32) {
  __shared__ __align__(16) char smem[32768];
  __hip_bfloat16* sA = (__hip_bfloat16*)smem;
  __hip_bfloat16* sB = (__hip_bfloat16*)(smem + 16384);
  __hip_bfloat16* sPb = (__hip_bfloat16*)smem;

  const int tid = threadIdx.x;
  const int wave = tid >> 6;
  const int lane = tid & 63;
  const int bid = blockIdx.x;
  const int jt = (bid & 7) * 4 + ((bid >> 3) & 3);
  const int mt = bid >> 5;
  const int m0 = mt * 128;
  const int j0 = jt * 32;

  f32x4 acc[4][4] = {};
  const int lrow = lane >> 3;
  const int lcol = ((lane & 7) ^ lrow) * 8;

  int brow_g[4];
#pragma unroll
  for (int i = 0; i < 4; ++i) {
    int n = wave * 32 + i * 8 + lrow;
    int q = n >> 6, gate = (n >> 4) & 3, u = n & 15;
    brow_g[i] = gate * HDIM + j0 + q * 16 + u;
  }
  const __hip_bfloat16* Abase =
      hprev + (size_t)(m0 + wave * 32 + lrow) * HDIM + lcol;

  const int mw = (wave >> 1) * 64;
  const int gn = wave & 1;
  const int u16 = lane & 15;
  const int k16q = lane >> 4;
  const int jo = gn * 16 + u16;
  const int j = j0 + jo;
  const int rb = m0 + mw + k16q * 4;
  float cpre[4][4];
#pragma unroll
  for (int mi = 0; mi < 4; ++mi)
#pragma unroll
    for (int r = 0; r < 4; ++r)
      cpre[mi][r] = c_in[(size_t)(rb + mi * 16 + r) * HDIM + j];

  for (int k0 = 0; k0 < HDIM; k0 += 64) {
#pragma unroll
    for (int i = 0; i < 4; ++i) {
      GLL16(Abase + i * 8 * HDIM + k0, &sA[(wave * 32 + i * 8) * 64]);
      GLL16(Whh + (size_t)brow_g[i] * HDIM + k0 + lcol,
            &sB[(wave * 32 + i * 8) * 64]);
    }
    __syncthreads();
#pragma unroll
    for (int kk = 0; kk < 64; kk += 32) {
      const int sl = (((kk >> 3) + k16q) ^ (u16 & 7)) * 8;
      short8 af[4], bf[4];
#pragma unroll
      for (int mi = 0; mi < 4; ++mi)
        af[mi] = *(const short8*)&sA[(mw + mi * 16 + u16) * 64 + sl];
#pragma unroll
      for (int ni = 0; ni < 4; ++ni)
        bf[ni] = *(const short8*)&sB[(gn * 64 + ni * 16 + u16) * 64 + sl];
#pragma unroll
      for (int mi = 0; mi < 4; ++mi)
#pragma unroll
        for (int ni = 0; ni < 4; ++ni)
          acc[mi][ni] = __builtin_amdgcn_mfma_f32_16x16x32_bf16(
              af[mi], bf[ni], acc[mi][ni], 0, 0, 0);
    }
    __syncthreads();
  }
  {
    const __hip_bfloat16* Pbj = Pb + (size_t)jt * 12288;
#pragma unroll
    for (int i = 0; i < 6; ++i)
      GLL16(Pbj + (wave * 6 + i) * 512 + lane * 8, &sPb[(wave * 6 + i) * 512]);
  }
  __syncthreads();
#pragma unroll
  for (int mi = 0; mi < 4; ++mi) {
#pragma unroll
    for (int r = 0; r < 4; ++r) {
      int row = rb + mi * 16 + r;
      int id = ids[row];
      const __hip_bfloat16* Pr = &sPb[id * 128 + jo];
      float iv = acc[mi][0][r] + __bfloat162float(Pr[0]);
      float fv = acc[mi][1][r] + __bfloat162float(Pr[32]);
      float gv = acc[mi][2][r] + __bfloat162float(Pr[64]);
      float ov = acc[mi][3][r] + __bfloat162float(Pr[96]);
      iv = sigmoidf_fast(iv);
      fv = sigmoidf_fast(fv);
      gv = tanhf_fast(gv);
      ov = sigmoidf_fast(ov);
      size_t off = (size_t)row * HDIM + j;
      float cc = fv * cpre[mi][r] + iv * gv;
      c_out[off] = cc;
      float hh = ov * tanhf_fast(cc);
      hnext[off] = __float2bfloat16(hh);
      if (LAST) hf32[off] = hh;
    }
  }
}

__global__ __launch_bounds__(256, 2) void scores_kernel(
    const __hip_bfloat16* __restrict__ h, const __hip_bfloat16* __restrict__ Wout,
    const float* __restrict__ bout, float* __restrict__ out) {
  __shared__ __align__(16) __hip_bfloat16 sA[128 * 128];
  __shared__ __align__(16) __hip_bfloat16 sB[96 * 128];
  const int tid = threadIdx.x;
  const int wave = tid >> 6, lane = tid & 63;
  const int u16 = lane & 15, k16q = lane >> 4;
  const long r0 = (long)blockIdx.x * 128;
  f32x4 acc[2][6] = {};
  const int srow4 = lane >> 4;
  const int sslot = lane & 15;
  for (int k0 = 0; k0 < HDIM; k0 += 128) {
#pragma unroll
    for (int i = 0; i < 8; ++i) {
      int row = wave * 32 + i * 4 + srow4;
      int gg2 = sslot ^ (row & 15);
      GLL16(h + (r0 + row) * HDIM + k0 + gg2 * 8,
            &sA[(wave * 32 + i * 4) * 128]);
    }
#pragma unroll
    for (int i = 0; i < 6; ++i) {
      int row = wave * 24 + i * 4 + srow4;
      int gg2 = sslot ^ (row & 15);
      GLL16(Wout + (size_t)row * HDIM + k0 + gg2 * 8,
            &sB[(wave * 24 + i * 4) * 128]);
    }
    __syncthreads();
#pragma unroll
    for (int kk = 0; kk < 128; kk += 32) {
      const int sl = (((kk >> 3) + k16q) ^ u16) * 8;
      short8 af[2], bf[6];
#pragma unroll
      for (int mi = 0; mi < 2; ++mi)
        af[mi] = *(const short8*)&sA[(wave * 32 + mi * 16 + u16) * 128 + sl];
#pragma unroll
      for (int ni = 0; ni < 6; ++ni)
        bf[ni] = *(const short8*)&sB[(ni * 16 + u16) * 128 + sl];
#pragma unroll
      for (int mi = 0; mi < 2; ++mi)
#pragma unroll
        for (int ni = 0; ni < 6; ++ni)
          acc[mi][ni] = __builtin_amdgcn_mfma_f32_16x16x32_bf16(
              af[mi], bf[ni], acc[mi][ni], 0, 0, 0);
    }
    __syncthreads();
  }
#pragma unroll
  for (int ni = 0; ni < 6; ++ni) {
    int v = ni * 16 + u16;
    float bv = bout[v];
#pragma unroll
    for (int mi = 0; mi < 2; ++mi)
#pragma unroll
      for (int r = 0; r < 4; ++r) {
        long grow = r0 + wave * 32 + mi * 16 + k16q * 4 + r;
        out[grow * VOCAB + v] = acc[mi][ni][r] + bv;
      }
  }
}

extern "C" void kernel_launch(void* const* d_in, const int* in_sizes, int n_in,
                              void* d_out, int out_size, void* d_ws, size_t ws_size,
                              hipStream_t stream) {
  const int* ids = (const int*)d_in[0];
  const float* h0 = (const float*)d_in[1];
  const float* c0 = (const float*)d_in[2];
  const float* emb = (const float*)d_in[3];
  const float* Wih = (const float*)d_in[4];
  const float* Whh_f = (const float*)d_in[5];
  const float* bih = (const float*)d_in[6];
  const float* bhh = (const float*)d_in[7];
  const float* Wout_f = (const float*)d_in[8];
  const float* bout = (const float*)d_in[9];

  float* out = (float*)d_out;
  float* scores = out;                              // T*B*V
  float* hT = out + (size_t)T_STEPS * BSZ * VOCAB;  // B*H
  float* cT = hT + (size_t)BSZ * HDIM;              // B*H

  const size_t BH = (size_t)BSZ * HDIM;
  char* w = (char*)d_ws;
  float* P = (float*)w;                      w += (size_t)VOCAB * 4096 * 4;
  __hip_bfloat16* Pb = (__hip_bfloat16*)w;   w += (size_t)32 * 12288 * 2;
  __hip_bfloat16* Whh = (__hip_bfloat16*)w;  w += (size_t)4 * HDIM * HDIM * 2;
  __hip_bfloat16* Wout = (__hip_bfloat16*)w; w += (size_t)VOCAB * HDIM * 2;
  __hip_bfloat16* h0b = (__hip_bfloat16*)w;  w += BH * 2;
  __hip_bfloat16* h1b = (__hip_bfloat16*)w;  w += BH * 2;

  prep_convert<<<dim3((4 * HDIM * HDIM + 255) / 256), dim3(256), 0, stream>>>(
      Whh_f, Wout_f, h0, Whh, Wout, h0b);
  prep_ptable<<<dim3((VOCAB * 4096) / 256), dim3(256), 0, stream>>>(
      emb, Wih, bih, bhh, P, Pb);

  // can the cooperative grid (1056 blocks) be co-resident?
  int per_cu = 0;
  hipError_t oe = hipOccupancyMaxActiveBlocksPerMultiprocessor(
      &per_cu, (const void*)lstm_persistent, 256, 0);
  bool coop = (oe == hipSuccess) && ((long)per_cu * 256 >= 1056);

  if (coop) {
    const int* a0 = ids;
    const __hip_bfloat16* a1 = Whh;
    const float* a2 = P;
    const __hip_bfloat16* a3 = Wout;
    const float* a4 = bout;
    const float* a5 = c0;
    __hip_bfloat16* a6 = h0b;
    __hip_bfloat16* a7 = h1b;
    float* a8 = scores;
    float* a9 = hT;
    float* a10 = cT;
    void* args[] = {&a0, &a1, &a2, &a3, &a4, &a5, &a6, &a7, &a8, &a9, &a10};
    hipLaunchCooperativeKernel((void*)lstm_persistent, dim3(1056), dim3(256),
                               args, 0, stream);
  } else {
    for (int t = 0; t < T_STEPS; ++t) {
      __hip_bfloat16* hp = (t & 1) ? h1b : h0b;
      __hip_bfloat16* hn = (t & 1) ? h0b : h1b;
      const float* cin = (t == 0) ? c0 : cT;
      if (t == T_STEPS - 1) {
        lstm_step_kernel<true><<<dim3(1024), dim3(256), 0, stream>>>(
            ids + (size_t)t * BSZ, hp, Whh, Pb, cin, cT, hn, hT);
      } else {
        lstm_step_kernel<false><<<dim3(1024), dim3(256), 0, stream>>>(
            ids + (size_t)t * BSZ, hp, Whh, Pb, cin, cT, hn, nullptr);
      }
      scores_kernel<<<dim3(BSZ / 128), dim3(256), 0, stream>>>(
          hn, Wout, bout, scores + (size_t)t * BSZ * VOCAB);
    }
  }
}

// Round 8
// 1114.108 us; speedup vs baseline: 1.2489x; 1.2489x over previous
//
#include <hip/hip_runtime.h>
#include <hip/hip_bf16.h>

// CharDecoder: T=21, B=4096, H=1024, E=50, V=96
// d_out: scores(T,B,V) fp32 | h_T(B,H) | c_T(B,H)

#define T_STEPS 21
#define BSZ 4096
#define HDIM 1024
#define VOCAB 96
#define EDIM 50

typedef __attribute__((ext_vector_type(8))) short short8;
typedef __attribute__((ext_vector_type(4))) float f32x4;

#define GLL16(g, l)                                                        \
  __builtin_amdgcn_global_load_lds(                                        \
      (const __attribute__((address_space(1))) void*)(g),                  \
      (__attribute__((address_space(3))) void*)(l), 16, 0, 0)

#define ASM_BARRIER() asm volatile("s_barrier" ::: "memory")
#define ASM_VMCNT8() asm volatile("s_waitcnt vmcnt(8)" ::: "memory")
#define ASM_VMCNT0() asm volatile("s_waitcnt vmcnt(0)" ::: "memory")

__device__ __forceinline__ float sigmoidf_fast(float x) {
  return 1.0f / (1.0f + __expf(-x));
}
__device__ __forceinline__ float tanhf_fast(float x) {
  return 2.0f / (1.0f + __expf(-2.0f * x)) - 1.0f;
}

// ---- prep: fp32 -> bf16 weight/state conversion -------------------------
__global__ void prep_convert(const float* __restrict__ Whh_f,
                             const float* __restrict__ Wout_f,
                             const float* __restrict__ h0,
                             __hip_bfloat16* __restrict__ Whh,
                             __hip_bfloat16* __restrict__ Wout,
                             __hip_bfloat16* __restrict__ hb0) {
  int idx = blockIdx.x * 256 + threadIdx.x;
  if (idx < 4 * HDIM * HDIM) {
    Whh[idx] = __float2bfloat16(Whh_f[idx]);
    hb0[idx] = __float2bfloat16(h0[idx]);
  }
  if (idx < VOCAB * HDIM) Wout[idx] = __float2bfloat16(Wout_f[idx]);
}

// ---- prep: Pb[jb][v][gate][32 units] (bf16) = emb.W_ih + b_ih + b_hh ----
__global__ void prep_ptable(const float* __restrict__ emb,
                            const float* __restrict__ Wih,
                            const float* __restrict__ bih,
                            const float* __restrict__ bhh,
                            __hip_bfloat16* __restrict__ Pb) {
  int idx = blockIdx.x * 256 + threadIdx.x;  // 96*4096
  int v = idx >> 12, g = idx & 4095;         // g = gate*1024 + j
  int gate = g >> 10, j = g & 1023;
  const float* er = emb + v * EDIM;
  const float* wr = Wih + g * EDIM;
  float s = bih[g] + bhh[g];
#pragma unroll 10
  for (int e = 0; e < EDIM; ++e) s += er[e] * wr[e];
  Pb[(size_t)(j >> 5) * 12288 + v * 128 + gate * 32 + (j & 31)] =
      __float2bfloat16(s);
}

// ---- fused LSTM step: 128 rows x 32 units, PIPELINED double-buffer ------
// Per K-iter: s_barrier (WAR on next buf) -> issue 8 GLL16 into next buf ->
// s_waitcnt vmcnt(8) (drains ONLY the previous iter's loads, ~1 iter old)
// -> s_barrier -> compute current buf. Loads stay in flight across the
// whole compute phase; no vmcnt(0) drain inside the loop. LDS 64 KB.
template <bool LAST>
__global__ __launch_bounds__(256, 2) void lstm_step_kernel(
    const int* __restrict__ ids,               // B ints (this t)
    const __hip_bfloat16* __restrict__ hprev,  // B x H
    const __hip_bfloat16* __restrict__ Whh,    // 4H x H (torch order i,f,g,o)
    const __hip_bfloat16* __restrict__ Pb,     // 32 x 96 x 128 (bf16)
    const float* __restrict__ c_in,            // B x H
    float* __restrict__ c_out,                 // B x H
    __hip_bfloat16* __restrict__ hnext,        // B x H
    float* __restrict__ hf32)                  // B x H (LAST only)
{
  __shared__ __align__(16) char smem[65536];  // buf0: [0,32K) buf1: [32K,64K)
  __hip_bfloat16* sPb = (__hip_bfloat16*)smem;  // [96][128] post-loop overlay

  const int tid = threadIdx.x;
  const int wave = tid >> 6;
  const int lane = tid & 63;
  const int bid = blockIdx.x;
  const int jt = (bid & 7) * 4 + ((bid >> 3) & 3);  // XCD swizzle
  const int mt = bid >> 5;
  const int m0 = mt * 128;
  const int j0 = jt * 32;

  f32x4 acc[4][4] = {};  // [m-frag][gate]

  // staging: wave stages 32 rows (4 issues x 8 rows); XOR swizzle on source
  const int lrow = lane >> 3;                // 0..7
  const int lcol = ((lane & 7) ^ lrow) * 8;  // swizzled chunk (elems)

  int brow_g[4];
#pragma unroll
  for (int i = 0; i < 4; ++i) {
    int n = wave * 32 + i * 8 + lrow;  // n' in [0,128)
    int q = n >> 6, gate = (n >> 4) & 3, u = n & 15;
    brow_g[i] = gate * HDIM + j0 + q * 16 + u;
  }
  const __hip_bfloat16* Abase =
      hprev + (size_t)(m0 + wave * 32 + lrow) * HDIM + lcol;
  const __hip_bfloat16* Bbase = Whh + lcol;

  const int mw = (wave >> 1) * 64;
  const int gn = wave & 1;
  const int u16 = lane & 15;
  const int k16q = lane >> 4;

  // epilogue coordinates (known early -> prefetch c_in)
  const int jo = gn * 16 + u16;  // j - j0
  const int j = j0 + jo;
  const int rb = m0 + mw + k16q * 4;
  float cpre[4][4];
#pragma unroll
  for (int mi = 0; mi < 4; ++mi)
#pragma unroll
    for (int r = 0; r < 4; ++r)
      cpre[mi][r] = c_in[(size_t)(rb + mi * 16 + r) * HDIM + j];

  // LDS slot base (elements) for this wave's staging issues
  const int sSlotA = wave * 32 * 64;  // within a buffer's sA region
  const int sSlotB = wave * 32 * 64;  // within a buffer's sB region

  // prologue: issue buffer 0 (k0 = 0)
  {
    __hip_bfloat16* nA = (__hip_bfloat16*)smem;
    __hip_bfloat16* nB = (__hip_bfloat16*)(smem + 16384);
#pragma unroll
    for (int i = 0; i < 4; ++i) {
      GLL16(Abase + i * 8 * HDIM, &nA[sSlotA + i * 8 * 64]);
      GLL16(Bbase + (size_t)brow_g[i] * HDIM, &nB[sSlotB + i * 8 * 64]);
    }
  }

  for (int it = 0; it < 16; ++it) {
    char* curb = smem + ((it & 1) << 15);
    char* nxtb = smem + ((~it & 1) << 15);
    const __hip_bfloat16* cA = (const __hip_bfloat16*)curb;
    const __hip_bfloat16* cB = (const __hip_bfloat16*)(curb + 16384);

    ASM_BARRIER();  // all waves done reading nxt buffer (WAR)
    if (it < 15) {
      __hip_bfloat16* nA = (__hip_bfloat16*)nxtb;
      __hip_bfloat16* nB = (__hip_bfloat16*)(nxtb + 16384);
      const int k0 = (it + 1) * 64;
#pragma unroll
      for (int i = 0; i < 4; ++i) {
        GLL16(Abase + i * 8 * HDIM + k0, &nA[sSlotA + i * 8 * 64]);
        GLL16(Bbase + (size_t)brow_g[i] * HDIM + k0, &nB[sSlotB + i * 8 * 64]);
      }
      ASM_VMCNT8();  // drain current buffer's 8 (issued one iter ago)
    } else {
      ASM_VMCNT0();
    }
    ASM_BARRIER();  // current buffer visible to all waves

#pragma unroll
    for (int kk = 0; kk < 64; kk += 32) {
      const int sl = (((kk >> 3) + k16q) ^ (u16 & 7)) * 8;
      short8 af[4], bf[4];
#pragma unroll
      for (int mi = 0; mi < 4; ++mi)
        af[mi] = *(const short8*)&cA[(mw + mi * 16 + u16) * 64 + sl];
#pragma unroll
      for (int ni = 0; ni < 4; ++ni)
        bf[ni] = *(const short8*)&cB[(gn * 64 + ni * 16 + u16) * 64 + sl];
#pragma unroll
      for (int mi = 0; mi < 4; ++mi)
#pragma unroll
        for (int ni = 0; ni < 4; ++ni)
          acc[mi][ni] = __builtin_amdgcn_mfma_f32_16x16x32_bf16(
              af[mi], bf[ni], acc[mi][ni], 0, 0, 0);
    }
  }

  // stage bf16 P-slice (24 KB) into buffer-0 region (last compute used buf1;
  // all waves passed the it=15 barrier, so buf0 is dead). Then one full sync.
  {
    const __hip_bfloat16* Pbj = Pb + (size_t)jt * 12288;
#pragma unroll
    for (int i = 0; i < 6; ++i)
      GLL16(Pbj + (wave * 6 + i) * 512 + lane * 8, &sPb[(wave * 6 + i) * 512]);
  }
  __syncthreads();

  // epilogue: all 4 gates of unit j live in this lane across n-frags
#pragma unroll
  for (int mi = 0; mi < 4; ++mi) {
#pragma unroll
    for (int r = 0; r < 4; ++r) {
      int row = rb + mi * 16 + r;
      int id = ids[row];
      const __hip_bfloat16* Pr = &sPb[id * 128 + jo];
      float iv = acc[mi][0][r] + __bfloat162float(Pr[0]);
      float fv = acc[mi][1][r] + __bfloat162float(Pr[32]);
      float gv = acc[mi][2][r] + __bfloat162float(Pr[64]);
      float ov = acc[mi][3][r] + __bfloat162float(Pr[96]);
      iv = sigmoidf_fast(iv);
      fv = sigmoidf_fast(fv);
      gv = tanhf_fast(gv);
      ov = sigmoidf_fast(ov);
      size_t off = (size_t)row * HDIM + j;
      float cc = fv * cpre[mi][r] + iv * gv;
      c_out[off] = cc;
      float hh = ov * tanhf_fast(cc);
      hnext[off] = __float2bfloat16(hh);
      if (LAST) hf32[off] = hh;
    }
  }
}

// ---- scores: LDS-tiled GEMM, 128 rows x 96 cols per block, BK=128 -------
__global__ __launch_bounds__(256, 2) void scores_kernel(
    const __hip_bfloat16* __restrict__ h,     // rows x H (bf16)
    const __hip_bfloat16* __restrict__ Wout,  // 96 x H
    const float* __restrict__ bout,           // 96
    float* __restrict__ out)                  // rows x 96
{
  __shared__ __align__(16) __hip_bfloat16 sA[128 * 128];  // 32 KB
  __shared__ __align__(16) __hip_bfloat16 sB[96 * 128];   // 24 KB

  const int tid = threadIdx.x;
  const int wave = tid >> 6, lane = tid & 63;
  const int u16 = lane & 15, k16q = lane >> 4;
  const long r0 = (long)blockIdx.x * 128;

  f32x4 acc[2][6] = {};  // wave: 32 rows x 96 cols

  const int srow4 = lane >> 4;  // staging: row within group of 4
  const int sslot = lane & 15;  // 16B slot within 256B row-chunk

  for (int k0 = 0; k0 < HDIM; k0 += 128) {
#pragma unroll
    for (int i = 0; i < 8; ++i) {  // A: 32 rows/wave
      int row = wave * 32 + i * 4 + srow4;
      int gg = sslot ^ (row & 15);
      GLL16(h + (r0 + row) * HDIM + k0 + gg * 8, &sA[(wave * 32 + i * 4) * 128]);
    }
#pragma unroll
    for (int i = 0; i < 6; ++i) {  // B: 24 rows/wave
      int row = wave * 24 + i * 4 + srow4;
      int gg = sslot ^ (row & 15);
      GLL16(Wout + (size_t)row * HDIM + k0 + gg * 8,
            &sB[(wave * 24 + i * 4) * 128]);
    }
    __syncthreads();
#pragma unroll
    for (int kk = 0; kk < 128; kk += 32) {
      const int sl = (((kk >> 3) + k16q) ^ u16) * 8;
      short8 af[2], bf[6];
#pragma unroll
      for (int mi = 0; mi < 2; ++mi)
        af[mi] = *(const short8*)&sA[(wave * 32 + mi * 16 + u16) * 128 + sl];
#pragma unroll
      for (int ni = 0; ni < 6; ++ni)
        bf[ni] = *(const short8*)&sB[(ni * 16 + u16) * 128 + sl];
#pragma unroll
      for (int mi = 0; mi < 2; ++mi)
#pragma unroll
        for (int ni = 0; ni < 6; ++ni)
          acc[mi][ni] = __builtin_amdgcn_mfma_f32_16x16x32_bf16(
              af[mi], bf[ni], acc[mi][ni], 0, 0, 0);
    }
    __syncthreads();
  }

#pragma unroll
  for (int ni = 0; ni < 6; ++ni) {
    int v = ni * 16 + u16;
    float bv = bout[v];
#pragma unroll
    for (int mi = 0; mi < 2; ++mi)
#pragma unroll
      for (int r = 0; r < 4; ++r) {
        long grow = r0 + wave * 32 + mi * 16 + k16q * 4 + r;
        out[grow * VOCAB + v] = acc[mi][ni][r] + bv;
      }
  }
}

extern "C" void kernel_launch(void* const* d_in, const int* in_sizes, int n_in,
                              void* d_out, int out_size, void* d_ws, size_t ws_size,
                              hipStream_t stream) {
  const int* ids = (const int*)d_in[0];
  const float* h0 = (const float*)d_in[1];
  const float* c0 = (const float*)d_in[2];
  const float* emb = (const float*)d_in[3];
  const float* Wih = (const float*)d_in[4];
  const float* Whh_f = (const float*)d_in[5];
  const float* bih = (const float*)d_in[6];
  const float* bhh = (const float*)d_in[7];
  const float* Wout_f = (const float*)d_in[8];
  const float* bout = (const float*)d_in[9];

  float* out = (float*)d_out;
  float* scores = out;                              // T*B*V
  float* hT = out + (size_t)T_STEPS * BSZ * VOCAB;  // B*H
  float* cT = hT + (size_t)BSZ * HDIM;              // B*H

  const size_t BH = (size_t)BSZ * HDIM;
  char* w = (char*)d_ws;
  __hip_bfloat16* Pb = (__hip_bfloat16*)w;   w += (size_t)32 * 12288 * 2;
  __hip_bfloat16* Whh = (__hip_bfloat16*)w;  w += (size_t)4 * HDIM * HDIM * 2;
  __hip_bfloat16* Wout = (__hip_bfloat16*)w; w += (size_t)VOCAB * HDIM * 2;
  __hip_bfloat16* hts = (__hip_bfloat16*)w;  // 22*BH (full) or 2*BH (pingpong)
  size_t base = (size_t)32 * 12288 * 2 + (size_t)4 * HDIM * HDIM * 2 +
                (size_t)VOCAB * HDIM * 2;
  const bool full = ws_size >= base + (size_t)(T_STEPS + 1) * BH * 2;

  prep_convert<<<dim3((4 * HDIM * HDIM + 255) / 256), dim3(256), 0, stream>>>(
      Whh_f, Wout_f, h0, Whh, Wout, hts);
  prep_ptable<<<dim3((VOCAB * 4096) / 256), dim3(256), 0, stream>>>(
      emb, Wih, bih, bhh, Pb);

  for (int t = 0; t < T_STEPS; ++t) {
    __hip_bfloat16* hp = hts + (full ? (size_t)t * BH : (size_t)(t & 1) * BH);
    __hip_bfloat16* hn =
        hts + (full ? (size_t)(t + 1) * BH : (size_t)((t + 1) & 1) * BH);
    const float* cin = (t == 0) ? c0 : cT;
    if (t == T_STEPS - 1) {
      lstm_step_kernel<true><<<dim3(1024), dim3(256), 0, stream>>>(
          ids + (size_t)t * BSZ, hp, Whh, Pb, cin, cT, hn, hT);
    } else {
      lstm_step_kernel<false><<<dim3(1024), dim3(256), 0, stream>>>(
          ids + (size_t)t * BSZ, hp, Whh, Pb, cin, cT, hn, nullptr);
    }
    if (!full) {
      scores_kernel<<<dim3(BSZ / 128), dim3(256), 0, stream>>>(
          hn, Wout, bout, scores + (size_t)t * BSZ * VOCAB);
    }
  }
  if (full) {
    scores_kernel<<<dim3(T_STEPS * BSZ / 128), dim3(256), 0, stream>>>(
        hts + BH, Wout, bout, scores);
  }
}